// Round 2
// baseline (589.974 us; speedup 1.0000x reference)
//
#include <hip/hip_runtime.h>

#define D    128
#define NF   3
#define V    8
#define ROWS 16

// ---- CSR-by-dst construction ------------------------------------------------

__global__ __launch_bounds__(256) void hist_kernel(
    const int* __restrict__ dst, int* __restrict__ count, int E)
{
    int t = blockIdx.x * 256 + threadIdx.x;
    if (t < E) atomicAdd(&count[dst[t]], 1);
}

// Single-workgroup exclusive scan over N counts (N=50000 -> 49 elems/thread).
__global__ __launch_bounds__(1024) void scan_kernel(
    const int* __restrict__ count, int* __restrict__ offset,
    int* __restrict__ cursor, int N)
{
    int tid = threadIdx.x;
    int chunk = (N + 1023) >> 10;
    int start = tid * chunk;
    int end = min(start + chunk, N);
    int s = 0;
    for (int i = start; i < end; ++i) s += count[i];

    int lane = tid & 63, wv = tid >> 6;
    int inc = s;
    for (int d = 1; d < 64; d <<= 1) {
        int u = __shfl_up(inc, d);
        if (lane >= d) inc += u;
    }
    __shared__ int wsum[16];
    if (lane == 63) wsum[wv] = inc;
    __syncthreads();
    int wbase = 0;
    for (int w = 0; w < wv; ++w) wbase += wsum[w];

    int run = wbase + inc - s;   // exclusive prefix for this thread's chunk
    for (int i = start; i < end; ++i) {
        offset[i] = run;
        cursor[i] = run;
        run += count[i];
    }
}

__global__ __launch_bounds__(256) void scatter_kernel(
    const int* __restrict__ dst, int* __restrict__ cursor,
    int* __restrict__ sorted, int E)
{
    int t = blockIdx.x * 256 + threadIdx.x;
    if (t < E) {
        int pos = atomicAdd(&cursor[dst[t]], 1);
        sorted[pos] = t;
    }
}

// ---- Fused gather + normalize + projection ---------------------------------
// 16 nodes per block, 128 threads (one per column).

__global__ __launch_bounds__(128) void fused_kernel(
    const float* __restrict__ nfeat,
    const int*   __restrict__ src,
    const int*   __restrict__ eidx,
    const float* __restrict__ emb,
    const int*   __restrict__ sorted,
    const int*   __restrict__ offset,
    const int*   __restrict__ count,
    const float* __restrict__ Wm,
    const float* __restrict__ bias,
    float* __restrict__ out,
    int N)
{
    __shared__ float sh[ROWS][D];
    int c = threadIdx.x;
    int row0 = blockIdx.x * ROWS;

    // Edge-embedding tables: 3*8 values per column -> 24 registers, zero
    // loads in the edge loop.
    float e0[V], e1[V], e2[V];
#pragma unroll
    for (int v = 0; v < V; ++v) {
        e0[v] = emb[(0 * V + v) * D + c];
        e1[v] = emb[(1 * V + v) * D + c];
        e2[v] = emb[(2 * V + v) * D + c];
    }

    for (int r = 0; r < ROWS; ++r) {
        int n = row0 + r;
        if (n >= N) { sh[r][c] = 0.0f; continue; }
        int off = offset[n];
        int cnt = count[n];
        float acc = nfeat[n * D + c];
        for (int j = 0; j < cnt; ++j) {
            int e = sorted[off + j];             // uniform across wave
            int s = src[e];                      // uniform
            int i0 = eidx[e * NF + 0];
            int i1 = eidx[e * NF + 1];
            int i2 = eidx[e * NF + 2];
            acc += nfeat[s * D + c] + e0[i0] + e1[i1] + e2[i2];
        }
        sh[r][c] = acc / (float)(cnt + 1);
    }
    __syncthreads();

    float bv = bias[c];
    float accs[ROWS];
#pragma unroll
    for (int r = 0; r < ROWS; ++r) accs[r] = bv;

    for (int k = 0; k < D; ++k) {
        float w = Wm[k * D + c];                 // coalesced
#pragma unroll
        for (int r = 0; r < ROWS; ++r)
            accs[r] += sh[r][k] * w;             // LDS broadcast
    }

#pragma unroll
    for (int r = 0; r < ROWS; ++r) {
        int n = row0 + r;
        if (n < N) out[n * D + c] = accs[r];
    }
}

extern "C" void kernel_launch(void* const* d_in, const int* in_sizes, int n_in,
                              void* d_out, int out_size, void* d_ws, size_t ws_size,
                              hipStream_t stream)
{
    const float* nfeat = (const float*)d_in[0];
    const int*   src   = (const int*)  d_in[1];
    const int*   dst   = (const int*)  d_in[2];
    const int*   eidx  = (const int*)  d_in[3];
    const float* emb   = (const float*)d_in[4];
    const float* Wm    = (const float*)d_in[5];
    const float* bias  = (const float*)d_in[6];
    float* out = (float*)d_out;

    int N = in_sizes[0] / D;   // 50000
    int E = in_sizes[1];       // 600000

    // ws layout: count[N] | offset[N] | cursor[N] | sorted[E]   (~3 MB)
    int* count  = (int*)d_ws;
    int* offset = count + N;
    int* cursor = offset + N;
    int* sorted = cursor + N;

    // ws is re-poisoned to 0xAA before every timed launch.
    hipMemsetAsync(count, 0, (size_t)N * sizeof(int), stream);

    int eb = (E + 255) / 256;
    hist_kernel<<<eb, 256, 0, stream>>>(dst, count, E);
    scan_kernel<<<1, 1024, 0, stream>>>(count, offset, cursor, N);
    scatter_kernel<<<eb, 256, 0, stream>>>(dst, cursor, sorted, E);
    fused_kernel<<<(N + ROWS - 1) / ROWS, 128, 0, stream>>>(
        nfeat, src, eidx, emb, sorted, offset, count, Wm, bias, out, N);
}

// Round 3
// 250.484 us; speedup vs baseline: 2.3553x; 2.3553x over previous
//
#include <hip/hip_runtime.h>

#define D  128
#define NF 3
#define V  8

// ---------------- CSR-by-dst build ----------------

__global__ __launch_bounds__(256) void hist_kernel(
    const int* __restrict__ dst, int* __restrict__ count, int E)
{
    int t = blockIdx.x * 256 + threadIdx.x;
    if (t < E) atomicAdd(&count[dst[t]], 1);
}

// per-block sums of count[]
__global__ __launch_bounds__(256) void bsum_kernel(
    const int* __restrict__ count, int* __restrict__ bsum, int N)
{
    int i = blockIdx.x * 256 + threadIdx.x;
    int v = (i < N) ? count[i] : 0;
#pragma unroll
    for (int d = 32; d > 0; d >>= 1) v += __shfl_down(v, d);
    __shared__ int ws[4];
    int lane = threadIdx.x & 63, wv = threadIdx.x >> 6;
    if (lane == 0) ws[wv] = v;
    __syncthreads();
    if (threadIdx.x == 0)
        bsum[blockIdx.x] = ws[0] + ws[1] + ws[2] + ws[3];
}

// single-block exclusive scan of nb (<=256) block sums
__global__ __launch_bounds__(256) void bscan_kernel(
    const int* __restrict__ bsum, int* __restrict__ bex, int nb)
{
    int t = threadIdx.x;
    int v = (t < nb) ? bsum[t] : 0;
    int lane = t & 63, wv = t >> 6;
    int inc = v;
#pragma unroll
    for (int d = 1; d < 64; d <<= 1) {
        int u = __shfl_up(inc, d);
        if (lane >= d) inc += u;
    }
    __shared__ int ws[4];
    if (lane == 63) ws[wv] = inc;
    __syncthreads();
    int base = 0;
    for (int w = 0; w < wv; ++w) base += ws[w];
    if (t < nb) bex[t] = base + inc - v;
}

// per-block exclusive scan + add block prefix -> offset & cursor
__global__ __launch_bounds__(256) void offsets_kernel(
    const int* __restrict__ count, const int* __restrict__ bex,
    int* __restrict__ offset, int* __restrict__ cursor, int N)
{
    int i = blockIdx.x * 256 + threadIdx.x;
    int c = (i < N) ? count[i] : 0;
    int lane = threadIdx.x & 63, wv = threadIdx.x >> 6;
    int inc = c;
#pragma unroll
    for (int d = 1; d < 64; d <<= 1) {
        int u = __shfl_up(inc, d);
        if (lane >= d) inc += u;
    }
    __shared__ int ws[4];
    if (lane == 63) ws[wv] = inc;
    __syncthreads();
    int base = bex[blockIdx.x];
    for (int w = 0; w < wv; ++w) base += ws[w];
    if (i < N) {
        int ex = base + inc - c;
        offset[i] = ex;
        cursor[i] = ex;
    }
}

// scatter packed (src | combined_emb_idx<<16) records into dst-sorted order
__global__ __launch_bounds__(256) void scatter_kernel(
    const int* __restrict__ src, const int* __restrict__ dst,
    const int* __restrict__ eidx, int* __restrict__ cursor,
    unsigned* __restrict__ packed, int E)
{
    int t = blockIdx.x * 256 + threadIdx.x;
    if (t < E) {
        int i0 = eidx[t * NF + 0];
        int i1 = eidx[t * NF + 1];
        int i2 = eidx[t * NF + 2];
        unsigned ci = (unsigned)(i0 + (i1 << 3) + (i2 << 6));   // [0,512)
        int pos = atomicAdd(&cursor[dst[t]], 1);
        packed[pos] = (unsigned)src[t] | (ci << 16);
    }
}

// combined embedding table: T[cmb][c] = e0[i0]+e1[i1]+e2[i2], 512x128 (256 KB)
__global__ __launch_bounds__(256) void table_kernel(
    const float* __restrict__ emb, float* __restrict__ T)
{
    int tid = blockIdx.x * 256 + threadIdx.x;   // 512*128 threads
    int cmb = tid >> 7, c = tid & 127;
    T[tid] = emb[((cmb & 7)) * D + c]
           + emb[(V + ((cmb >> 3) & 7)) * D + c]
           + emb[(2 * V + (cmb >> 6)) * D + c];
}

// ---------------- gather: one wave per node ----------------
// lane l holds cols [2l, 2l+1]; writes normalized h row into d_out.

__global__ __launch_bounds__(256) void gather_kernel(
    const float* __restrict__ nfeat,
    const unsigned* __restrict__ packed,
    const int* __restrict__ offset,
    const int* __restrict__ count,
    const float* __restrict__ T,
    float* __restrict__ hout,
    int N)
{
    int wid = (blockIdx.x * 256 + threadIdx.x) >> 6;   // node id
    int lane = threadIdx.x & 63;
    if (wid >= N) return;

    const float2* nf2 = (const float2*)nfeat;
    const float2* T2  = (const float2*)T;

    int off = offset[wid];
    int cnt = count[wid];
    float2 acc = nf2[wid * 64 + lane];

    for (int base = 0; base < cnt; base += 64) {
        int m = min(64, cnt - base);
        unsigned rec = (lane < m) ? packed[off + base + lane] : 0u;
        int j = 0;
        for (; j + 4 <= m; j += 4) {
            unsigned u0 = __shfl((int)rec, j);
            unsigned u1 = __shfl((int)rec, j + 1);
            unsigned u2 = __shfl((int)rec, j + 2);
            unsigned u3 = __shfl((int)rec, j + 3);
            float2 a0 = nf2[(u0 & 0xFFFFu) * 64 + lane];
            float2 t0 = T2[(u0 >> 16) * 64 + lane];
            float2 a1 = nf2[(u1 & 0xFFFFu) * 64 + lane];
            float2 t1 = T2[(u1 >> 16) * 64 + lane];
            float2 a2 = nf2[(u2 & 0xFFFFu) * 64 + lane];
            float2 t2 = T2[(u2 >> 16) * 64 + lane];
            float2 a3 = nf2[(u3 & 0xFFFFu) * 64 + lane];
            float2 t3 = T2[(u3 >> 16) * 64 + lane];
            acc.x += (a0.x + t0.x) + (a1.x + t1.x) + (a2.x + t2.x) + (a3.x + t3.x);
            acc.y += (a0.y + t0.y) + (a1.y + t1.y) + (a2.y + t2.y) + (a3.y + t3.y);
        }
        for (; j < m; ++j) {
            unsigned u = __shfl((int)rec, j);
            float2 a = nf2[(u & 0xFFFFu) * 64 + lane];
            float2 t = T2[(u >> 16) * 64 + lane];
            acc.x += a.x + t.x;
            acc.y += a.y + t.y;
        }
    }

    float inv = 1.0f / (float)(cnt + 1);
    acc.x *= inv; acc.y *= inv;
    ((float2*)hout)[wid * 64 + lane] = acc;
}

// ---------------- projection: out = h @ W + b (in-place on d_out) ----------

__global__ __launch_bounds__(128) void proj_kernel(
    const float* __restrict__ Wm, const float* __restrict__ bias,
    float* __restrict__ out, int N)
{
    __shared__ float sh[16][D];
    int c = threadIdx.x;
    int row0 = blockIdx.x * 16;

    for (int r = 0; r < 16; ++r) {
        int n = row0 + r;
        sh[r][c] = (n < N) ? out[n * D + c] : 0.0f;
    }
    __syncthreads();

    float acc[16];
    float bv = bias[c];
#pragma unroll
    for (int r = 0; r < 16; ++r) acc[r] = bv;

    for (int k4 = 0; k4 < D / 4; ++k4) {
        int k = k4 * 4;
        float w0 = Wm[(k + 0) * D + c];
        float w1 = Wm[(k + 1) * D + c];
        float w2 = Wm[(k + 2) * D + c];
        float w3 = Wm[(k + 3) * D + c];
#pragma unroll
        for (int r = 0; r < 16; ++r) {
            float4 hv = ((const float4*)sh[r])[k4];   // LDS broadcast, b128
            acc[r] += hv.x * w0 + hv.y * w1 + hv.z * w2 + hv.w * w3;
        }
    }

#pragma unroll
    for (int r = 0; r < 16; ++r) {
        int n = row0 + r;
        if (n < N) out[n * D + c] = acc[r];
    }
}

extern "C" void kernel_launch(void* const* d_in, const int* in_sizes, int n_in,
                              void* d_out, int out_size, void* d_ws, size_t ws_size,
                              hipStream_t stream)
{
    const float* nfeat = (const float*)d_in[0];
    const int*   src   = (const int*)  d_in[1];
    const int*   dst   = (const int*)  d_in[2];
    const int*   eidx  = (const int*)  d_in[3];
    const float* emb   = (const float*)d_in[4];
    const float* Wm    = (const float*)d_in[5];
    const float* bias  = (const float*)d_in[6];
    float* out = (float*)d_out;

    int N = in_sizes[0] / D;   // 50000
    int E = in_sizes[1];       // 600000
    int NB = (N + 255) / 256;  // 196

    // ws: count[N] | cursor[N] | offset[N] | bsum[256] | bex[256] | packed[E] | T[512*128]
    int* count  = (int*)d_ws;
    int* cursor = count + N;
    int* offset = cursor + N;
    int* bsum   = offset + N;
    int* bex    = bsum + 256;
    unsigned* packed = (unsigned*)(bex + 256);
    float* T = (float*)(packed + E);

    hipMemsetAsync(count, 0, (size_t)N * sizeof(int), stream);

    int eb = (E + 255) / 256;
    hist_kernel<<<eb, 256, 0, stream>>>(dst, count, E);
    bsum_kernel<<<NB, 256, 0, stream>>>(count, bsum, N);
    bscan_kernel<<<1, 256, 0, stream>>>(bsum, bex, NB);
    offsets_kernel<<<NB, 256, 0, stream>>>(count, bex, offset, cursor, N);
    scatter_kernel<<<eb, 256, 0, stream>>>(src, dst, eidx, cursor, packed, E);
    table_kernel<<<512 * 128 / 256, 256, 0, stream>>>(emb, T);

    gather_kernel<<<(N * 64 + 255) / 256, 256, 0, stream>>>(
        nfeat, packed, offset, count, T, out, N);
    proj_kernel<<<(N + 15) / 16, 128, 0, stream>>>(Wm, bias, out, N);
}